// Round 5
// baseline (29.719 us; speedup 1.0000x reference)
//
#include <hip/hip_runtime.h>

// EdgeOrientation2mer v4b: 16 edges/block, 16 threads/edge, 4 pairs/thread.
// Each thread's 12 output floats are contiguous (48 B) -> LDS staging at
// stride-3 f4 (odd stride = naturally conflict-free both phases, no swizzle).
// LDS = 12 KB -> full 32-wave/CU occupancy. Nontemporal streaming stores
// via ext_vector_type (HIP float4 rejected by the builtin).

constexpr int Bq = 2, Nq = 2048, Kq = 48;
constexpr float EPS = 0.1f;

typedef float vf4 __attribute__((ext_vector_type(4)));

struct F3 { float x, y, z; };
__device__ __forceinline__ F3 f3sub(F3 a, F3 b) { return {a.x - b.x, a.y - b.y, a.z - b.z}; }
__device__ __forceinline__ float f3dot(F3 a, F3 b) {
    return fmaf(a.x, b.x, fmaf(a.y, b.y, a.z * b.z));
}
__device__ __forceinline__ F3 f3scale(F3 a, float s) { return {a.x * s, a.y * s, a.z * s}; }
__device__ __forceinline__ F3 f3normed(F3 v) {
    float inv = rsqrtf(f3dot(v, v) + EPS);
    return f3scale(v, inv);
}
__device__ __forceinline__ F3 f3cross(F3 a, F3 b) {
    return {a.y * b.z - a.z * b.y, a.z * b.x - a.x * b.z, a.x * b.y - a.y * b.x};
}

__global__ __launch_bounds__(256) void edge_orient_v4_kernel(
    const float* __restrict__ X,   // [B,N,4,3]
    const int* __restrict__ E,     // [B,N,K]
    const int* __restrict__ C,     // [B,N]
    float* __restrict__ out)       // [B,N,K,192]
{
    __shared__ vf4 smem[768];               // 12 KB: block's 16-edge output span

    const int t = threadIdx.x;
    const unsigned edge = blockIdx.x * 16u + (unsigned)(t >> 4);
    const unsigned sub  = t & 15u;          // 16 threads per edge
    const unsigned a    = sub >> 1;         // row 0..7
    const unsigned half = sub & 1u;         // b-half: 0 -> atoms i, 1 -> atoms j

    const unsigned node = edge / (unsigned)Kq;
    const unsigned bidx = node >> 11;
    const int j = E[edge];
    const unsigned nodej = (bidx << 11) + (unsigned)j;

    const float m = (C[node] > 0 && C[nodej] > 0) ? 1.0f : 0.0f;

    const vf4* Xi4 = reinterpret_cast<const vf4*>(X + (size_t)node * 12);
    const vf4* Xj4 = reinterpret_cast<const vf4*>(X + (size_t)nodej * 12);
    const vf4 A0 = Xi4[0], A1 = Xi4[1], A2 = Xi4[2];

    // Frame from node-i atoms N, CA, C; fold mask in.
    const F3 p0 = {A0.x, A0.y, A0.z};
    const F3 p1 = {A0.w, A1.x, A1.y};
    const F3 p2 = {A1.z, A1.w, A2.x};
    const F3 n1u = f3normed(f3sub(p0, p1));
    const F3 uC  = f3normed(f3sub(p2, p1));
    const F3 n2u = f3normed(f3cross(n1u, uC));
    const F3 n3u = f3normed(f3cross(n1u, n2u));
    const F3 n1 = f3scale(n1u, m), n2 = f3scale(n2u, m), n3 = f3scale(n3u, m);

    // This thread's 4 b-atoms: node i's (half=0) or node j's (half=1).
    const vf4* Pb4 = half ? Xj4 : Xi4;      // pointer select, no divergence
    const vf4 Q0 = Pb4[0], Q1 = Pb4[1], Q2 = Pb4[2];
    const F3 q0 = {Q0.x, Q0.y, Q0.z};
    const F3 q1 = {Q0.w, Q1.x, Q1.y};
    const F3 q2 = {Q1.z, Q1.w, Q2.x};
    const F3 q3 = {Q2.y, Q2.z, Q2.w};

    // Row atom a (direct scalar loads; a is 0..7 -> i or j).
    const float* pap = X + (size_t)(a < 4u ? node : nodej) * 12 + (a & 3u) * 3;
    const F3 pa = {pap[0], pap[1], pap[2]};

    float o[12] __attribute__((aligned(16)));
#pragma unroll
    for (int k = 0; k < 4; ++k) {
        F3 pb;
        switch (k) {
            case 0: pb = q0; break; case 1: pb = q1; break;
            case 2: pb = q2; break; default: pb = q3; break;
        }
        const F3 d = f3sub(pb, pa);
        const float nn = fmaf(d.x, d.x, fmaf(d.y, d.y, fmaf(d.z, d.z, EPS)));
        const float inv = rsqrtf(nn);
        o[k * 3 + 0] = f3dot(d, n1) * inv;
        o[k * 3 + 1] = f3dot(d, n2) * inv;
        o[k * 3 + 2] = f3dot(d, n3) * inv;
    }

    // Stage: thread t's 3 f4 are logical f4 3t..3t+2 of the block span.
    // Odd stride 3 -> per-instruction banks spread over all groups: free.
    const vf4* ov = reinterpret_cast<const vf4*>(o);
#pragma unroll
    for (int i = 0; i < 3; ++i) smem[3 * t + i] = ov[i];
    __syncthreads();

    // Coalesced streaming writeback: 3 x 4 KB lane-contiguous nt stores.
    vf4* outb = reinterpret_cast<vf4*>(out) + (size_t)blockIdx.x * 768;
#pragma unroll
    for (int s = 0; s < 3; ++s) {
        const int g = s * 256 + t;
        __builtin_nontemporal_store(smem[g], &outb[g]);
    }
}

extern "C" void kernel_launch(void* const* d_in, const int* in_sizes, int n_in,
                              void* d_out, int out_size, void* d_ws, size_t ws_size,
                              hipStream_t stream) {
    const float* X = (const float*)d_in[0];
    const int*   E = (const int*)d_in[1];
    const int*   C = (const int*)d_in[2];
    float* out = (float*)d_out;

    const int total_edges = Bq * Nq * Kq;     // 196,608
    dim3 block(256);
    dim3 grid(total_edges / 16);              // 12,288 blocks, exact
    edge_orient_v4_kernel<<<grid, block, 0, stream>>>(X, E, C, out);
}